// Round 3
// baseline (26338.245 us; speedup 1.0000x reference)
//
#include <hip/hip_runtime.h>

#define T_SEQ 8192
#define POISON 0xAAAAAAAAu

typedef float vfloat4 __attribute__((ext_vector_type(4)));

static __device__ __forceinline__ float sigm(float x)  { return 1.0f / (1.0f + __expf(-x)); }
static __device__ __forceinline__ float tanhq(float x) { return 1.0f - 2.0f / (__expf(2.0f * x) + 1.0f); }

// Publish: SYSTEM-scope (sc0 sc1) wave-coalesced store -> write-through so the
// line lands in L3 whole (R5). mode 2: each producer owns a FULL 64B line.
static __device__ __forceinline__ void sysStore4(float* p, vfloat4 v) {
  asm volatile("global_store_dwordx4 %0, %1, off sc0 sc1" :: "v"(p), "v"(v) : "memory");
}
// Poll: AGENT-scope (sc1 only) -> served by L3 (R4). Data IS the sentinel
// (harness 0xAA ws-poison).
static __device__ __forceinline__ vfloat4 pollLoad4(const float* p) {
  vfloat4 v;
  asm volatile("global_load_dwordx4 %0, %1, off sc1\n\ts_waitcnt vmcnt(0)"
               : "=v"(v) : "v"(p) : "memory");
  return v;
}
static __device__ __forceinline__ bool valid4(vfloat4 v) {
  return (__float_as_uint(v[0]) != POISON) && (__float_as_uint(v[1]) != POISON) &&
         (__float_as_uint(v[2]) != POISON) && (__float_as_uint(v[3]) != POISON);
}
// R10: NO initial backoff — in the fused pipeline the poll of h0[t] happens a
// full phase-B (~300-400ns) after its publish, which replaces R9's fixed 768cy
// sleep. h1 polls have a whole iteration of slack -> first-try hits.
static __device__ __forceinline__ vfloat4 pollRow(const float* src, int* gd) {
  vfloat4 v;
  for (;;) {
    v = pollLoad4(src);
    if (valid4(v)) break;
    if (--(*gd) <= 0) break;
    __builtin_amdgcn_s_sleep(2);               // ~128 cy retry spacing
  }
  return v;
}

// LDS pad-swizzle (R3-proven: SQ_LDS_BANK_CONFLICT=0): word i -> i + (i>>6)*4.
#define SWZ(i) ((i) + (((i) >> 6) << 2))

// 48 named float4 weight locals (192 VGPR), pinned INSIDE the step loop.
// Extends the R3..R8-proven 16-float4 idiom; safe shape remains 256-thr
// blocks + launch_bounds(256,1) (1 block/CU -> 512 VGPR budget).
#define WL(X) X(0) X(1) X(2) X(3) X(4) X(5) X(6) X(7) X(8) X(9) X(10) X(11) X(12) X(13) X(14) X(15)
#define DECLA(k) float4 WA##k = wpA[k];
#define DECLI(k) float4 WI##k = wpI[k];
#define DECLH(k) float4 WH##k = wpH[k];
#define PINA(k)  asm volatile("" : "+v"(WA##k.x), "+v"(WA##k.y), "+v"(WA##k.z), "+v"(WA##k.w));
#define PINI(k)  asm volatile("" : "+v"(WI##k.x), "+v"(WI##k.y), "+v"(WI##k.z), "+v"(WI##k.w));
#define PINH(k)  asm volatile("" : "+v"(WH##k.x), "+v"(WH##k.y), "+v"(WH##k.z), "+v"(WH##k.w));
#define FMA_A(k) { float4 hv = hp0[k]; \
  a0 = __builtin_fmaf(WA##k.x, hv.x, a0); a1 = __builtin_fmaf(WA##k.y, hv.y, a1); \
  a2 = __builtin_fmaf(WA##k.z, hv.z, a2); a3 = __builtin_fmaf(WA##k.w, hv.w, a3); }
#define FMA_I(k) { float4 hv = hp0[k]; \
  a0 = __builtin_fmaf(WI##k.x, hv.x, a0); a1 = __builtin_fmaf(WI##k.y, hv.y, a1); \
  a2 = __builtin_fmaf(WI##k.z, hv.z, a2); a3 = __builtin_fmaf(WI##k.w, hv.w, a3); }
#define FMA_H(k) { float4 hv = hp1[k]; \
  a0 = __builtin_fmaf(WH##k.x, hv.x, a0); a1 = __builtin_fmaf(WH##k.y, hv.y, a1); \
  a2 = __builtin_fmaf(WH##k.z, hv.z, a2); a3 = __builtin_fmaf(WH##k.w, hv.w, a3); }

// R10 fused pipeline: 64 blocks, each owns h0 rows [wg*8, wg*8+8) AND the
// matching h1 rows. Per iteration t (t = 0..T inclusive):
//   stage: tid<128 poll h0[t-1]; tid>=128 poll h1[t-2] (1-iter slack)
//   phase A (t<T):  h0[t] = LSTM0(h0[t-1], x[t]);  publish EARLY
//   phase B (t>=1): h1[t-1] = LSTM1(h1[t-2], h0[t-1]);  publish
//   -> phase B's ~300-400ns of FMAs hides h0's publish->L3->poll RTT.
// mode 2 (ws >= 64MB): both h-buffers padded rows of 1024 fl; block's 8 h at
//   wg*16, dup'd into the upper half-line -> 1 producer/64B line, full-line
//   writes. mode 0: dense 512-fl rows (R8-proven fallback).
__global__ __launch_bounds__(256, 1) void lstm_fused(
    const float* __restrict__ input_seq,
    const float* __restrict__ w_ih0, const float* __restrict__ w_hh0,
    const float* __restrict__ b_ih0, const float* __restrict__ b_hh0,
    const float* __restrict__ w_ih1, const float* __restrict__ w_hh1,
    const float* __restrict__ b_ih1, const float* __restrict__ b_hh1,
    float* __restrict__ h0buf, float* __restrict__ h1buf, int mode)
{
  __shared__ float xin[T_SEQ];                   // 32 KB
  __shared__ __align__(16) float hb[2][1088];    // double-buffered: h0 row | h1 row (swizzled)
  __shared__ __align__(16) float hstA[8];        // h0 publish gather
  __shared__ __align__(16) float hstB[8];        // h1 publish gather
  const int tid  = threadIdx.x;
  const int lane = tid & 63;
  const int wv   = tid >> 6;                     // 0..3
  const int wg   = blockIdx.x;                   // 0..63
  const int hs   = (mode == 2) ? 1024 : 512;     // mailbox row stride (floats)
  int gd = 1 << 22;                              // poll budget: break, don't hang

  for (int i = tid; i < T_SEQ; i += 256) xin[i] = input_seq[i];

  const int q  = tid & 7;                        // K-chunk (64 floats)
  const int lr = tid >> 3;                       // gate-row 0..31
  const int jl = lr >> 2;                        // local h 0..7
  const int g  = lr & 3;                         // gate (i,f,g,o)
  const int grow = g * 512 + wg * 8 + jl;        // same row index for L0 and L1
  const float4* wpA = (const float4*)(w_hh0 + (size_t)grow * 512 + q * 64);
  const float4* wpI = (const float4*)(w_ih1 + (size_t)grow * 512 + q * 64);
  const float4* wpH = (const float4*)(w_hh1 + (size_t)grow * 512 + q * 64);
  WL(DECLA) WL(DECLI) WL(DECLH)
  const float wx    = w_ih0[grow];
  const float biasA = b_ih0[grow] + b_hh0[grow];
  const float biasB = b_ih1[grow] + b_hh1[grow];
  const int hsIdx = wv * 2 + (lane >> 5);        // == jl for the (lane&31)==0 writers
  const int pq  = (tid < 128) ? tid : (tid - 128);       // quad index 0..127
  const int off = (mode == 2) ? ((pq >> 1) * 16 + (pq & 1) * 4) : (4 * pq);
  float cA = 0.0f, cB = 0.0f;
  __syncthreads();                               // xin ready

  for (int t = 0; t <= T_SEQ; ++t) {
    WL(PINA) WL(PINI) WL(PINH)                   // loop-carried: no weight remat
    float* hl = hb[t & 1];
    if (tid < 128) {                             // h0[t-1]
      vfloat4 v;
      if (t == 0) { v[0] = v[1] = v[2] = v[3] = 0.0f; }
      else        { v = pollRow(h0buf + (size_t)(t - 1) * hs + off, &gd); }
      *(vfloat4*)&hl[SWZ(4 * tid)] = v;
    } else {                                     // h1[t-2] (1 iteration of slack)
      vfloat4 v;
      if (t <= 1) { v[0] = v[1] = v[2] = v[3] = 0.0f; }
      else        { v = pollRow(h1buf + (size_t)(t - 2) * hs + off, &gd); }
      *(vfloat4*)&hl[544 + SWZ(4 * (tid - 128))] = v;
    }
    __syncthreads();
    const float4* hp0 = (const float4*)(hl + q * 68);          // h0[t-1] chunk
    const float4* hp1 = (const float4*)(hl + 544 + q * 68);    // h1[t-2] chunk

    // ---------------- phase A: h0[t] ----------------
    if (t < T_SEQ) {
      float a0 = 0.f, a1 = 0.f, a2 = 0.f, a3 = 0.f;
      WL(FMA_A)
      float acc = (a0 + a1) + (a2 + a3);
      acc += __shfl_xor(acc, 1);                 // reduce over 8 K-chunks
      acc += __shfl_xor(acc, 2);
      acc += __shfl_xor(acc, 4);
      float pre = acc + biasA + wx * xin[t];
      float pf = __shfl_xor(pre, 8);             // gather f,g,o pre-acts
      float pg = __shfl_xor(pre, 16);
      float po = __shfl_xor(pre, 24);
      float i_ = sigm(pre), f_ = sigm(pf), g_ = tanhq(pg), o_ = sigm(po);
      cA = f_ * cA + i_ * g_;
      float h = o_ * tanhq(cA);
      if ((lane & 31) == 0) hstA[hsIdx] = h;
    }
    __syncthreads();
    if (t < T_SEQ) {                             // publish h0[t] ASAP (fire & forget)
      if (mode == 2) {
        if (tid < 4) sysStore4(h0buf + (size_t)t * 1024 + wg * 16 + tid * 4,
                               *(vfloat4*)&hstA[(tid & 1) * 4]);
      } else {
        if (tid < 2) sysStore4(h0buf + (size_t)t * 512 + wg * 8 + tid * 4,
                               *(vfloat4*)&hstA[4 * tid]);
      }
    }

    // ---------------- phase B: h1[t-1] (hides h0 RTT) ----------------
    if (t >= 1) {
      float a0 = 0.f, a1 = 0.f, a2 = 0.f, a3 = 0.f;
      WL(FMA_I)                                  // w_ih1 . h0[t-1]
      WL(FMA_H)                                  // w_hh1 . h1[t-2]
      float acc = (a0 + a1) + (a2 + a3);
      acc += __shfl_xor(acc, 1);
      acc += __shfl_xor(acc, 2);
      acc += __shfl_xor(acc, 4);
      float pre = acc + biasB;
      float pf = __shfl_xor(pre, 8);
      float pg = __shfl_xor(pre, 16);
      float po = __shfl_xor(pre, 24);
      float i_ = sigm(pre), f_ = sigm(pf), g_ = tanhq(pg), o_ = sigm(po);
      cB = f_ * cB + i_ * g_;
      float h = o_ * tanhq(cB);
      if ((lane & 31) == 0) hstB[hsIdx] = h;
    }
    __syncthreads();
    if (t >= 1) {                                // publish h1[t-1]
      if (mode == 2) {
        if (tid < 4) sysStore4(h1buf + (size_t)(t - 1) * 1024 + wg * 16 + tid * 4,
                               *(vfloat4*)&hstB[(tid & 1) * 4]);
      } else {
        if (tid < 2) sysStore4(h1buf + (size_t)(t - 1) * 512 + wg * 8 + tid * 4,
                               *(vfloat4*)&hstB[4 * tid]);
      }
    }
  }
}

// ---------------- MLP head on the final hidden state ----------------
__global__ void lstm_head(const float* __restrict__ h1buf,
                          const float* __restrict__ w1, const float* __restrict__ b1,
                          const float* __restrict__ w2, const float* __restrict__ b2,
                          float* __restrict__ out, int mode)
{
  const int lane = threadIdx.x;     // 64 threads
  const int h1s = (mode == 2) ? 1024 : 512;
  const float* h2 = h1buf + (size_t)(T_SEQ - 1) * h1s;
  float hv[8];
  #pragma unroll
  for (int k = 0; k < 8; ++k) {
    int jj = lane * 8 + k;
    int off = (mode == 2) ? ((jj >> 3) * 16 + (jj & 7))   // block b's 8 h at b*16
                          : jj;                            // dense
    hv[k] = h2[off];
  }
  float o = 0.0f;
  for (int r = 0; r < 20; ++r) {
    const float* wr = w1 + r * 512 + lane * 8;
    float p = 0.0f;
    #pragma unroll
    for (int k = 0; k < 8; ++k) p += wr[k] * hv[k];
    #pragma unroll
    for (int m = 1; m < 64; m <<= 1) p += __shfl_xor(p, m);
    o += w2[r] * (p + b1[r]);
  }
  if (lane == 0) out[0] = o + b2[0];
}

extern "C" void kernel_launch(void* const* d_in, const int* in_sizes, int n_in,
                              void* d_out, int out_size, void* d_ws, size_t ws_size,
                              hipStream_t stream)
{
  const float* input_seq = (const float*)d_in[0];
  const float* w_ih0 = (const float*)d_in[1];
  const float* w_hh0 = (const float*)d_in[2];
  const float* b_ih0 = (const float*)d_in[3];
  const float* b_hh0 = (const float*)d_in[4];
  const float* w_ih1 = (const float*)d_in[5];
  const float* w_hh1 = (const float*)d_in[6];
  const float* b_ih1 = (const float*)d_in[7];
  const float* b_hh1 = (const float*)d_in[8];
  const float* w1 = (const float*)d_in[9];
  const float* b1 = (const float*)d_in[10];
  const float* w2 = (const float*)d_in[11];
  const float* b2 = (const float*)d_in[12];
  (void)in_sizes; (void)n_in; (void)out_size;

  char* ws = (char*)d_ws;
  float* h0buf = (float*)ws;
  const size_t needA = (size_t)T_SEQ * 1024 * 4 * 2;   // 64 MB (padded x2)
  int mode;
  float* h1buf;
  if (ws_size >= needA) { mode = 2; h1buf = (float*)(ws + (size_t)T_SEQ * 1024 * 4); }
  else                  { mode = 0; h1buf = (float*)(ws + (size_t)T_SEQ * 512 * 4); }

  hipLaunchKernelGGL(lstm_fused, dim3(64), dim3(256), 0, stream,
                     input_seq, w_ih0, w_hh0, b_ih0, b_hh0,
                     w_ih1, w_hh1, b_ih1, b_hh1, h0buf, h1buf, mode);
  hipLaunchKernelGGL(lstm_head, dim3(1), dim3(64), 0, stream,
                     h1buf, w1, b1, w2, b2, (float*)d_out, mode);
}

// Round 5
// 24002.913 us; speedup vs baseline: 1.0973x; 1.0973x over previous
//
#include <hip/hip_runtime.h>

#define T_SEQ 8192
#define POISON 0xAAAAAAAAu

typedef float vfloat4 __attribute__((ext_vector_type(4)));

static __device__ __forceinline__ float sigm(float x)  { return 1.0f / (1.0f + __expf(-x)); }
static __device__ __forceinline__ float tanhq(float x) { return 1.0f - 2.0f / (__expf(2.0f * x) + 1.0f); }

// Publish: SYSTEM-scope (sc0 sc1) 16B store -> write-through, lands in L3 whole
// sector (R5/R8-proven granularity).
static __device__ __forceinline__ void sysStore4(float* p, vfloat4 v) {
  asm volatile("global_store_dwordx4 %0, %1, off sc0 sc1" :: "v"(p), "v"(v) : "memory");
}
// Poll: AGENT-scope (sc1 only) -> served by L3 (R4-proven). Data IS the
// sentinel (harness 0xAA ws-poison).
static __device__ __forceinline__ vfloat4 pollLoad4(const float* p) {
  vfloat4 v;
  asm volatile("global_load_dwordx4 %0, %1, off sc1\n\ts_waitcnt vmcnt(0)"
               : "=v"(v) : "v"(p) : "memory");
  return v;
}
static __device__ __forceinline__ bool valid4(vfloat4 v) {
  return (__float_as_uint(v[0]) != POISON) && (__float_as_uint(v[1]) != POISON) &&
         (__float_as_uint(v[2]) != POISON) && (__float_as_uint(v[3]) != POISON);
}
// Data load after flag-gate: first try expected to hit; retry loop is the
// correctness belt (validity still decided by the DATA, never the flag alone).
static __device__ __forceinline__ vfloat4 pollRow(const float* src, int* gd) {
  vfloat4 v;
  for (;;) {
    v = pollLoad4(src);
    if (valid4(v)) break;
    if (--(*gd) <= 0) break;
    __builtin_amdgcn_s_sleep(1);               // 64 cy spacing
  }
  return v;
}
// R12: release-flag poll. Producer stores stamp (t+1) AFTER vmcnt(0)-completed
// data stores -> stamp visible at L3 implies data visible at L3. One dword per
// lane, wave-coalesced (~8 lines/wave-sample) -> kills the 41K-stream poll
// storm that caused R9's L3 queueing. Stamp (not counter): no atomic
// serialization, and idempotent across non-repoisoned reps.
static __device__ __forceinline__ void pollFlag(const float* p, unsigned int want, int* gd) {
  for (;;) {
    unsigned int c;
    asm volatile("global_load_dword %0, %1, off sc1\n\ts_waitcnt vmcnt(0)"
                 : "=v"(c) : "v"(p) : "memory");
    if (c == want) return;
    if (--(*gd) <= 0) return;
    __builtin_amdgcn_s_sleep(1);
  }
}

// LDS pad-swizzle (R3-proven: SQ_LDS_BANK_CONFLICT=0): word i -> i + (i>>6)*4.
#define SWZ(i) ((i) + (((i) >> 6) << 2))

// 16 named float4 weight locals, pinned INSIDE the step loop. ONLY safe shape
// (R3..R8 evidence): 256-thr blocks + launch_bounds(256,1).
#define WLIST(X) X(0) X(1) X(2) X(3) X(4) X(5) X(6) X(7) X(8) X(9) X(10) X(11) X(12) X(13) X(14) X(15)
#define DECLW(k) float4 W##k = wp4[k];
#define PINW(k)  asm volatile("" : "+v"(W##k.x), "+v"(W##k.y), "+v"(W##k.z), "+v"(W##k.w));
#define DOFMA(k) { float4 hv = hp4[k]; \
  a0 = __builtin_fmaf(W##k.x, hv.x, a0); a1 = __builtin_fmaf(W##k.y, hv.y, a1); \
  a2 = __builtin_fmaf(W##k.z, hv.z, a2); a3 = __builtin_fmaf(W##k.w, hv.w, a3); }

// blocks 0..63   : layer 0. 32 gate-rows (8 h x 4 g), 8 thr/row (K=512).
// blocks 64..191 : layer 1. 16 gate-rows (4 h x 4 g), 16 thr/row (K=1024).
// h0: dense [T][512]. h1: padded [T][1024], block-exclusive quads (R8-proven).
// mode 1: flag-gated (needs 72MB ws). mode 0: R9 backoff polling (48MB).
__global__ __launch_bounds__(256, 1) void lstm_main(
    const float* __restrict__ input_seq,
    const float* __restrict__ w_ih0, const float* __restrict__ w_hh0,
    const float* __restrict__ b_ih0, const float* __restrict__ b_hh0,
    const float* __restrict__ w_ih1, const float* __restrict__ w_hh1,
    const float* __restrict__ b_ih1, const float* __restrict__ b_hh1,
    float* __restrict__ h0buf, float* __restrict__ h1buf,
    float* __restrict__ flags0, float* __restrict__ flags1, int mode)
{
  __shared__ float xin[T_SEQ];                   // 32 KB (layer-0 blocks only)
  __shared__ __align__(16) float hb[2][1088];    // double-buffered swizzled h rows
  __shared__ __align__(16) float hstage[8];      // gather slot for publish
  const int tid  = threadIdx.x;
  const int lane = tid & 63;
  const int wv   = tid >> 6;                     // 0..3
  const int wg   = blockIdx.x;
  int gd = 1 << 22;                              // poll budget: break, don't hang

  if (wg < 64) {
    // ================= layer 0 (K=512) =================
    for (int i = tid; i < T_SEQ; i += 256) xin[i] = input_seq[i];
    const int q  = tid & 7;                      // K-chunk (64 floats)
    const int lr = tid >> 3;                     // gate-row 0..31
    const int jl = lr >> 2;                      // local h 0..7
    const int g  = lr & 3;                       // gate (i,f,g,o)
    const int grow = g * 512 + wg * 8 + jl;
    const float4* wp4 = (const float4*)(w_hh0 + (size_t)grow * 512 + q * 64);
    WLIST(DECLW)
    const float wx   = w_ih0[grow];
    const float bias = b_ih0[grow] + b_hh0[grow];
    const int hsIdx = wv * 2 + (lane >> 5);      // hstage slot for lanes 0,32 (== jl)
    float c = 0.0f;
    __syncthreads();                             // xin ready

    for (int t = 0; t < T_SEQ; ++t) {
      WLIST(PINW)                                // loop-carried: no weight remat
      float* hl = hb[t & 1];
      if (tid < 128) {                           // stage h0[t-1] quad tid
        vfloat4 v;
        if (t == 0) { v[0] = v[1] = v[2] = v[3] = 0.0f; }
        else {
          if (mode) pollFlag(flags0 + ((size_t)(t - 1) * 64 + (tid >> 1)) * 4,
                             (unsigned)t, &gd);
          else      __builtin_amdgcn_s_sleep(12);        // R9 contention backoff
          v = pollRow(h0buf + (size_t)(t - 1) * 512 + 4 * tid, &gd);
        }
        *(vfloat4*)&hl[SWZ(4 * tid)] = v;
      }
      __syncthreads();
      const float4* hp4 = (const float4*)(hl + q * 68);
      float a0 = 0.f, a1 = 0.f, a2 = 0.f, a3 = 0.f;
      WLIST(DOFMA)
      float acc = (a0 + a1) + (a2 + a3);
      acc += __shfl_xor(acc, 1);                 // reduce over 8 K-chunks
      acc += __shfl_xor(acc, 2);
      acc += __shfl_xor(acc, 4);
      float pre = acc + bias + wx * xin[t];
      float pf = __shfl_xor(pre, 8);             // gather f,g,o pre-acts
      float pg = __shfl_xor(pre, 16);
      float po = __shfl_xor(pre, 24);
      float i_ = sigm(pre), f_ = sigm(pf), g_ = tanhq(pg), o_ = sigm(po);
      c = f_ * c + i_ * g_;
      float h = o_ * tanhq(c);
      if ((lane & 31) == 0) hstage[hsIdx] = h;   // gather 8 h into LDS
      __syncthreads();
      if (tid == 0) {                            // publish data, then release-flag
        sysStore4(h0buf + (size_t)t * 512 + wg * 8,     *(vfloat4*)&hstage[0]);
        sysStore4(h0buf + (size_t)t * 512 + wg * 8 + 4, *(vfloat4*)&hstage[4]);
        if (mode) {
          asm volatile("s_waitcnt vmcnt(0)" ::: "memory");  // data AT L3 before flag
          vfloat4 st; st[0] = st[1] = st[2] = st[3] = __uint_as_float((unsigned)(t + 1));
          sysStore4(flags0 + ((size_t)t * 64 + wg) * 4, st);
        }
      }
    }
  } else {
    // ================= layer 1 (K=1024: h0|h1) =================
    const int wg1 = wg - 64;                     // 0..127
    const int q  = tid & 15;                     // 0..7 -> w_ih1/h0, 8..15 -> w_hh1/h1
    const int lr = tid >> 4;                     // 0..15
    const int jl = lr >> 2;                      // 0..3 (== wv)
    const int g  = lr & 3;
    const int grow = g * 512 + wg1 * 4 + jl;
    const float* wsrc = (q < 8) ? (w_ih1 + (size_t)grow * 512 + q * 64)
                                : (w_hh1 + (size_t)grow * 512 + (q - 8) * 64);
    const float4* wp4 = (const float4*)wsrc;
    WLIST(DECLW)
    const float bias = b_ih1[grow] + b_hh1[grow];
    const int blkOff = (wg1 >> 1) * 16 + (wg1 & 1) * 4;  // exclusive quad (padded h1)
    const int chunkOff = (q < 8) ? q * 68 : 544 + (q - 8) * 68;  // 544 = SWZ(512)
    const int p2 = (tid >= 128) ? (tid - 128) : 0;
    const int srcOff = (p2 >> 1) * 16 + (p2 & 1) * 4;
    float c = 0.0f;
    __syncthreads();

    for (int t = 0; t < T_SEQ; ++t) {
      WLIST(PINW)                                // loop-carried: no weight remat
      float* hl = hb[t & 1];
      vfloat4 v;
      if (tid < 128) {                           // h0[t] (produced by L0 at its step t)
        if (mode) pollFlag(flags0 + ((size_t)t * 64 + (tid >> 1)) * 4,
                           (unsigned)(t + 1), &gd);
        else      __builtin_amdgcn_s_sleep(12);
        v = pollRow(h0buf + (size_t)t * 512 + 4 * tid, &gd);
        *(vfloat4*)&hl[SWZ(4 * tid)] = v;
      } else {                                   // h1[t-1] (zeros at t==0)
        if (t == 0) { v[0] = v[1] = v[2] = v[3] = 0.0f; }
        else {
          if (mode) pollFlag(flags1 + ((size_t)(t - 1) * 128 + p2) * 4,
                             (unsigned)t, &gd);
          else      __builtin_amdgcn_s_sleep(12);
          v = pollRow(h1buf + (size_t)(t - 1) * 1024 + srcOff, &gd);
        }
        *(vfloat4*)&hl[544 + SWZ(4 * p2)] = v;
      }
      __syncthreads();
      const float4* hp4 = (const float4*)(hl + chunkOff);
      float a0 = 0.f, a1 = 0.f, a2 = 0.f, a3 = 0.f;
      WLIST(DOFMA)
      float acc = (a0 + a1) + (a2 + a3);
      acc += __shfl_xor(acc, 1);                 // reduce over 16 K-chunks
      acc += __shfl_xor(acc, 2);
      acc += __shfl_xor(acc, 4);
      acc += __shfl_xor(acc, 8);
      float pre = acc + bias;
      float pf = __shfl_xor(pre, 16);
      float pg = __shfl_xor(pre, 32);
      float po = __shfl_xor(pre, 48);
      float i_ = sigm(pre), f_ = sigm(pf), g_ = tanhq(pg), o_ = sigm(po);
      c = f_ * c + i_ * g_;
      float h = o_ * tanhq(c);
      if (lane == 0) hstage[wv] = h;             // gather 4 h into LDS
      __syncthreads();
      if (tid == 0) {                            // publish data, then release-flag
        sysStore4(h1buf + (size_t)t * 1024 + blkOff, *(vfloat4*)&hstage[0]);
        if (mode) {
          asm volatile("s_waitcnt vmcnt(0)" ::: "memory");
          vfloat4 st; st[0] = st[1] = st[2] = st[3] = __uint_as_float((unsigned)(t + 1));
          sysStore4(flags1 + ((size_t)t * 128 + wg1) * 4, st);
        }
      }
    }
  }
}

// ---------------- MLP head on the final hidden state ----------------
__global__ void lstm_head(const float* __restrict__ h1buf,
                          const float* __restrict__ w1, const float* __restrict__ b1,
                          const float* __restrict__ w2, const float* __restrict__ b2,
                          float* __restrict__ out)
{
  const int lane = threadIdx.x;     // 64 threads
  const float* h2 = h1buf + (size_t)(T_SEQ - 1) * 1024;   // padded h1 row
  float hv[8];
  #pragma unroll
  for (int k = 0; k < 8; ++k) {
    int jj = lane * 8 + k;
    hv[k] = h2[(jj >> 3) * 16 + (jj & 7)];       // padded layout: block j>>2's quad
  }
  float o = 0.0f;
  for (int r = 0; r < 20; ++r) {
    const float* wr = w1 + r * 512 + lane * 8;
    float p = 0.0f;
    #pragma unroll
    for (int k = 0; k < 8; ++k) p += wr[k] * hv[k];
    #pragma unroll
    for (int m = 1; m < 64; m <<= 1) p += __shfl_xor(p, m);
    o += w2[r] * (p + b1[r]);
  }
  if (lane == 0) out[0] = o + b2[0];
}

extern "C" void kernel_launch(void* const* d_in, const int* in_sizes, int n_in,
                              void* d_out, int out_size, void* d_ws, size_t ws_size,
                              hipStream_t stream)
{
  const float* input_seq = (const float*)d_in[0];
  const float* w_ih0 = (const float*)d_in[1];
  const float* w_hh0 = (const float*)d_in[2];
  const float* b_ih0 = (const float*)d_in[3];
  const float* b_hh0 = (const float*)d_in[4];
  const float* w_ih1 = (const float*)d_in[5];
  const float* w_hh1 = (const float*)d_in[6];
  const float* b_ih1 = (const float*)d_in[7];
  const float* b_hh1 = (const float*)d_in[8];
  const float* w1 = (const float*)d_in[9];
  const float* b1 = (const float*)d_in[10];
  const float* w2 = (const float*)d_in[11];
  const float* b2 = (const float*)d_in[12];
  (void)in_sizes; (void)n_in; (void)out_size;

  char* ws = (char*)d_ws;
  const size_t H0_B = (size_t)T_SEQ * 512 * 4;             // 16 MB
  const size_t H1_B = (size_t)T_SEQ * 1024 * 4;            // 32 MB (padded)
  const size_t F0_B = (size_t)T_SEQ * 64 * 16;             //  8 MB (16B/producer)
  const size_t F1_B = (size_t)T_SEQ * 128 * 16;            // 16 MB
  float* h0buf  = (float*)ws;
  float* h1buf  = (float*)(ws + H0_B);
  float* flags0 = (float*)(ws + H0_B + H1_B);
  float* flags1 = (float*)(ws + H0_B + H1_B + F0_B);
  const size_t need1 = H0_B + H1_B + F0_B + F1_B;          // 72 MB
  const size_t need0 = H0_B + H1_B;                        // 48 MB
  int mode = (ws_size >= need1) ? 1 : 0;
  (void)need0;

  hipLaunchKernelGGL(lstm_main, dim3(192), dim3(256), 0, stream,
                     input_seq, w_ih0, w_hh0, b_ih0, b_hh0,
                     w_ih1, w_hh1, b_ih1, b_hh1,
                     h0buf, h1buf, flags0, flags1, mode);
  hipLaunchKernelGGL(lstm_head, dim3(1), dim3(64), 0, stream,
                     h1buf, w1, b1, w2, b2, (float*)d_out);
}